// Round 1
// baseline (209.910 us; speedup 1.0000x reference)
//
#include <hip/hip_runtime.h>

typedef unsigned short ushort_t;
typedef __attribute__((ext_vector_type(8))) short short8;
typedef __attribute__((ext_vector_type(4))) float floatx4;

// Problem constants
// B=512, S=64, N=8, D=64, A=16, H=256, IN_DIM=640

__device__ __forceinline__ float mish_f(float x) {
    // mish(x) = x * tanh(softplus(x)) = x * (w-2)/w, w = e^2x + 2e^x + 2
    float e = __expf(x);
    float w = fmaf(e, e + 2.0f, 2.0f);   // >= 2 always
    return x - 2.0f * x * __builtin_amdgcn_rcpf(w);
}

__device__ __forceinline__ ushort_t f2bf(float f) {
    unsigned int u = __float_as_uint(f);
    unsigned int r = (u + 0x7fffu + ((u >> 16) & 1u)) >> 16;  // RNE
    return (ushort_t)r;
}

// ---------------- prep: obsW[b,h], actW[b,n,j,h], W2T bf16 ----------------
__global__ void prep_kernel(const float* __restrict__ state,
                            const float* __restrict__ action,
                            const float* __restrict__ W1,
                            const float* __restrict__ W2,
                            float* __restrict__ obsW,
                            float* __restrict__ actW,
                            ushort_t* __restrict__ W2T) {
    int bid = blockIdx.x;
    int t = threadIdx.x;
    if (bid < 512) {
        int b = bid;
        __shared__ float st[512];
        __shared__ float ac[128];
        __shared__ float w1a[16 * 256];
        st[t] = state[b * 512 + t];
        st[256 + t] = state[b * 512 + 256 + t];
        if (t < 128) ac[t] = action[b * 128 + t];
        __syncthreads();
        // obsW[b][t] = sum_f state[b][f] * W1[f][t]
        float acc = 0.0f;
#pragma unroll 8
        for (int f = 0; f < 512; ++f) acc += st[f] * W1[f * 256 + t];
        obsW[b * 256 + t] = acc;
        // actW[b][n][j][t] = sum_a action[b][n][a] * W1[512 + j*16 + a][t]
        for (int j = 0; j < 8; ++j) {
            __syncthreads();
#pragma unroll
            for (int r = 0; r < 16; ++r) w1a[r * 256 + t] = W1[(512 + j * 16 + r) * 256 + t];
            __syncthreads();
            for (int n = 0; n < 8; ++n) {
                float a2 = 0.0f;
#pragma unroll
                for (int a = 0; a < 16; ++a) a2 += ac[n * 16 + a] * w1a[a * 256 + t];
                actW[(((size_t)b * 8 + n) * 8 + j) * 256 + t] = a2;
            }
        }
    } else {
        // W2T[n][k] = bf16(W2[k][n]); blocks 512..575, 4 n-rows each
        int nbase = (bid - 512) * 4;
        int n = nbase + (t >> 6);
        int klo = (t & 63);
        for (int kk = 0; kk < 4; ++kk) {
            int k = kk * 64 + klo;
            W2T[n * 256 + k] = f2bf(W2[k * 256 + n]);
        }
    }
}

// ---------------- main: build h1 (prefix+mish), layer2 MFMA GEMM, layer3 dot ----------------
#define LDK 264  // padded LDS row stride (bf16 elems): 264*2=528B, 528/4=132 words, 132%32=4

__global__ __launch_bounds__(256, 2) void main_kernel(
        const float* __restrict__ obsW, const float* __restrict__ actW,
        const ushort_t* __restrict__ W2T, const int* __restrict__ perm,
        const float* __restrict__ b1, const float* __restrict__ b2,
        const float* __restrict__ W3, const float* __restrict__ b3,
        float* __restrict__ qk) {
    __shared__ ushort_t h1[128 * LDK];   // 67.6 KB
    __shared__ float obsb[256];
    __shared__ int perm_s[16 * 8];
    __shared__ float qpart[4][128];

    int t = threadIdx.x;
    int bid = blockIdx.x;
    int b = bid >> 2;
    int sg = bid & 3;
    int s0 = sg * 16;

    obsb[t] = obsW[b * 256 + t] + b1[t];
    if (t < 128) perm_s[t] = perm[((size_t)b * 64 + s0) * 8 + t];
    __syncthreads();

    // ---- build h1 rows: row r = sl*8 + k holds mish(obsW + b1 + prefix_k) ----
    const float* actb = actW + (size_t)b * 64 * 256;
    for (int sl = 0; sl < 16; ++sl) {
        float run = obsb[t];
#pragma unroll
        for (int j = 0; j < 8; ++j) {
            int p = perm_s[sl * 8 + j];
            run += actb[(p * 8 + j) * 256 + t];
            h1[(sl * 8 + j) * LDK + t] = f2bf(mish_f(run));
        }
    }
    __syncthreads();

    // ---- layer2: M=128, N=256, K=256; wave w owns 64-col N-strip ----
    int w = t >> 6;
    int L = t & 63;
    int lo = L & 15;
    int q = L >> 4;

    floatx4 acc[8][4];
#pragma unroll
    for (int mt = 0; mt < 8; ++mt)
#pragma unroll
        for (int nt = 0; nt < 4; ++nt)
            acc[mt][nt] = (floatx4){0.f, 0.f, 0.f, 0.f};

    const ushort_t* w2base = W2T + ((size_t)(w * 64 + lo)) * 256 + q * 8;

#pragma unroll
    for (int ks = 0; ks < 8; ++ks) {
        short8 afr[8];
#pragma unroll
        for (int mt = 0; mt < 8; ++mt) {
            const ushort_t* ap = &h1[(mt * 16 + lo) * LDK + ks * 32 + q * 8];
            afr[mt] = *reinterpret_cast<const short8*>(ap);
        }
        short8 bfr[4];
#pragma unroll
        for (int nt = 0; nt < 4; ++nt)
            bfr[nt] = *reinterpret_cast<const short8*>(w2base + nt * 16 * 256 + ks * 32);
#pragma unroll
        for (int mt = 0; mt < 8; ++mt)
#pragma unroll
            for (int nt = 0; nt < 4; ++nt)
                acc[mt][nt] = __builtin_amdgcn_mfma_f32_16x16x32_bf16(afr[mt], bfr[nt], acc[mt][nt], 0, 0, 0);
    }

    // ---- epilogue: h2 = mish(acc + b2), layer3 partial dot with W3 ----
    float b2c[4], w3c[4];
#pragma unroll
    for (int nt = 0; nt < 4; ++nt) {
        int col = w * 64 + nt * 16 + lo;
        b2c[nt] = b2[col];
        w3c[nt] = W3[col];
    }
#pragma unroll
    for (int mt = 0; mt < 8; ++mt) {
        float part[4] = {0.f, 0.f, 0.f, 0.f};
#pragma unroll
        for (int nt = 0; nt < 4; ++nt) {
#pragma unroll
            for (int r = 0; r < 4; ++r) {
                float h2 = mish_f(acc[mt][nt][r] + b2c[nt]);
                part[r] = fmaf(h2, w3c[nt], part[r]);
            }
        }
#pragma unroll
        for (int r = 0; r < 4; ++r) {
            float v = part[r];
            v += __shfl_xor(v, 1);
            v += __shfl_xor(v, 2);
            v += __shfl_xor(v, 4);
            v += __shfl_xor(v, 8);
            if (lo == 0) qpart[w][mt * 16 + q * 4 + r] = v;
        }
    }
    __syncthreads();
    if (t < 128) {
        float qv = qpart[0][t] + qpart[1][t] + qpart[2][t] + qpart[3][t] + b3[0];
        qk[((size_t)b * 64 + s0) * 8 + t] = qv;  // row t = sl*8 + k
    }
}

// ---------------- final: q1[b,i] = mean_s qk[b,s,perm[b,s,i]] ----------------
__global__ void final_kernel(const float* __restrict__ qk,
                             const int* __restrict__ perm,
                             float* __restrict__ out) {
    int b = blockIdx.x;
    int t = threadIdx.x;  // 64 threads
    __shared__ float qs[512];
    __shared__ int ps[512];
    for (int r = 0; r < 8; ++r) {
        qs[r * 64 + t] = qk[(size_t)b * 512 + r * 64 + t];
        ps[r * 64 + t] = perm[(size_t)b * 512 + r * 64 + t];
    }
    __syncthreads();
    int i = t & 7;
    int s0 = t >> 3;
    float v = 0.0f;
    for (int s = s0; s < 64; s += 8) v += qs[s * 8 + ps[s * 8 + i]];
    v += __shfl_xor(v, 8);
    v += __shfl_xor(v, 16);
    v += __shfl_xor(v, 32);
    if (t < 8) {
        float r = v * (1.0f / 64.0f);
        out[b * 8 + t] = r;
        out[4096 + b * 8 + t] = r;
    }
}

extern "C" void kernel_launch(void* const* d_in, const int* in_sizes, int n_in,
                              void* d_out, int out_size, void* d_ws, size_t ws_size,
                              hipStream_t stream) {
    const float* state  = (const float*)d_in[0];
    const float* action = (const float*)d_in[1];
    const float* W1     = (const float*)d_in[2];
    const float* b1     = (const float*)d_in[3];
    const float* W2     = (const float*)d_in[4];
    const float* b2     = (const float*)d_in[5];
    const float* W3     = (const float*)d_in[6];
    const float* b3     = (const float*)d_in[7];
    const int*   perm   = (const int*)d_in[8];
    float* out = (float*)d_out;

    char* ws = (char*)d_ws;
    float*    obsW = (float*)ws;                                   // 512*256*4   = 0.5 MB
    float*    actW = (float*)(ws + 524288);                        // 512*64*256*4 = 32 MB
    ushort_t* W2T  = (ushort_t*)(ws + 524288 + 33554432);          // 128 KB
    float*    qk   = (float*)(ws + 524288 + 33554432 + 131072);    // 1 MB

    prep_kernel<<<576, 256, 0, stream>>>(state, action, W1, W2, obsW, actW, W2T);
    main_kernel<<<2048, 256, 0, stream>>>(obsW, actW, W2T, perm, b1, b2, W3, b3, qk);
    final_kernel<<<512, 64, 0, stream>>>(qk, perm, out);
}

// Round 2
// 198.832 us; speedup vs baseline: 1.0557x; 1.0557x over previous
//
#include <hip/hip_runtime.h>

typedef unsigned short ushort_t;
typedef __attribute__((ext_vector_type(8))) short short8;
typedef __attribute__((ext_vector_type(4))) float floatx4;

// B=512, S=64, N=8, D=64, A=16, H=256, IN_DIM=640

__device__ __forceinline__ float mish_f(float x) {
    float e = __expf(x);
    float w = fmaf(e, e + 2.0f, 2.0f);   // e^2x + 2e^x + 2, >= 2
    return x - 2.0f * x * __builtin_amdgcn_rcpf(w);
}

__device__ __forceinline__ unsigned f2bf_u(float f) {
    unsigned int u = __float_as_uint(f);
    return (u + 0x7fffu + ((u >> 16) & 1u)) >> 16;  // RNE
}

// ---------------- prep: obsW[b,h]+b1, actW[b,n,j,h], W2T bf16 ----------------
__global__ __launch_bounds__(256) void prep_kernel(
        const float* __restrict__ state,
        const float* __restrict__ action,
        const float* __restrict__ W1,
        const float* __restrict__ b1,
        const float* __restrict__ W2,
        float* __restrict__ obsW,
        float* __restrict__ actW,
        ushort_t* __restrict__ W2T) {
    int bid = blockIdx.x;
    int t = threadIdx.x;
    if (bid < 512) {
        int b = bid;
        const float* stp = state + (size_t)b * 512;   // wave-uniform reads -> s_load
        const float* acp = action + (size_t)b * 128;  // wave-uniform reads -> s_load

        // obsW[b][t] = sum_f state[b][f] * W1[f][t]  (4 independent chains)
        float a0 = 0.f, a1 = 0.f, a2 = 0.f, a3 = 0.f;
#pragma unroll 8
        for (int f = 0; f < 512; f += 4) {
            a0 = fmaf(stp[f + 0], W1[(f + 0) * 256 + t], a0);
            a1 = fmaf(stp[f + 1], W1[(f + 1) * 256 + t], a1);
            a2 = fmaf(stp[f + 2], W1[(f + 2) * 256 + t], a2);
            a3 = fmaf(stp[f + 3], W1[(f + 3) * 256 + t], a3);
        }
        obsW[b * 256 + t] = (a0 + a1) + (a2 + a3) + b1[t];

        // actW[b][n][j][t] = sum_a action[b][n][a] * W1[512 + j*16 + a][t]
        const float* W1a = W1 + 512 * 256;
        for (int j = 0; j < 8; ++j) {
            float acc[8];
#pragma unroll
            for (int n = 0; n < 8; ++n) acc[n] = 0.f;
#pragma unroll
            for (int a = 0; a < 16; ++a) {
                float w = W1a[(j * 16 + a) * 256 + t];
#pragma unroll
                for (int n = 0; n < 8; ++n)
                    acc[n] = fmaf(acp[n * 16 + a], w, acc[n]);
            }
#pragma unroll
            for (int n = 0; n < 8; ++n)
                actW[(((size_t)b * 8 + n) * 8 + j) * 256 + t] = acc[n];
        }
    } else {
        // W2T[n][k] = bf16(W2[k][n]); blocks 512..575, 4 n-rows each
        int n = (bid - 512) * 4 + (t >> 6);
        int klo = (t & 63);
        for (int kk = 0; kk < 4; ++kk) {
            int k = kk * 64 + klo;
            W2T[n * 256 + k] = (ushort_t)f2bf_u(W2[k * 256 + n]);
        }
    }
}

// ---------------- main: build h1 (prefix+mish), layer2 MFMA, layer3 dot ----------------
#define LDK 264  // padded LDS row stride in bf16 elems (multiple of 8 for b128 reads)

__global__ __launch_bounds__(256, 4) void main_kernel(
        const float* __restrict__ obsW, const float* __restrict__ actW,
        const ushort_t* __restrict__ W2T, const int* __restrict__ perm,
        const float* __restrict__ b2,
        const float* __restrict__ W3, const float* __restrict__ b3,
        float* __restrict__ qk) {
    __shared__ ushort_t h1[64 * LDK];   // 33.8 KB
    __shared__ float obsb[256];
    __shared__ int perm_s[64];
    __shared__ float qpart[4][64];

    int t = threadIdx.x;
    int bid = blockIdx.x;
    int b = bid >> 3;
    int sg = bid & 7;
    int s0 = sg * 8;

    obsb[t] = obsW[b * 256 + t];           // already includes b1
    if (t < 64) perm_s[t] = perm[((size_t)b * 64 + s0) * 8 + t];
    __syncthreads();

    // ---- build h1 rows (row = sl*8 + j): 2 cols per thread, 4 sl per thread ----
    const float* actb = actW + (size_t)b * 64 * 256;
    {
        int half = t >> 7;
        int c = (t & 127) * 2;
        float ob0 = obsb[c], ob1 = obsb[c + 1];
#pragma unroll
        for (int sl2 = 0; sl2 < 4; ++sl2) {
            int sl = half * 4 + sl2;
            float r0 = ob0, r1 = ob1;
#pragma unroll
            for (int j = 0; j < 8; ++j) {
                int p = perm_s[sl * 8 + j];
                float2 av = *reinterpret_cast<const float2*>(actb + (p * 8 + j) * 256 + c);
                r0 += av.x;
                r1 += av.y;
                unsigned pk = f2bf_u(mish_f(r0)) | (f2bf_u(mish_f(r1)) << 16);
                *reinterpret_cast<unsigned*>(&h1[(sl * 8 + j) * LDK + c]) = pk;
            }
        }
    }
    __syncthreads();

    // ---- layer2: M=64, N=256, K=256; wave w owns 64-col N-strip ----
    int w = t >> 6;
    int lo = t & 15;
    int q = (t >> 4) & 3;

    floatx4 acc[4][4];
#pragma unroll
    for (int mt = 0; mt < 4; ++mt)
#pragma unroll
        for (int nt = 0; nt < 4; ++nt)
            acc[mt][nt] = (floatx4){0.f, 0.f, 0.f, 0.f};

    const ushort_t* w2base = W2T + ((size_t)(w * 64 + lo)) * 256 + q * 8;

#pragma unroll
    for (int ks = 0; ks < 8; ++ks) {
        short8 afr[4];
#pragma unroll
        for (int mt = 0; mt < 4; ++mt)
            afr[mt] = *reinterpret_cast<const short8*>(&h1[(mt * 16 + lo) * LDK + ks * 32 + q * 8]);
        short8 bfr[4];
#pragma unroll
        for (int nt = 0; nt < 4; ++nt)
            bfr[nt] = *reinterpret_cast<const short8*>(w2base + nt * 16 * 256 + ks * 32);
#pragma unroll
        for (int mt = 0; mt < 4; ++mt)
#pragma unroll
            for (int nt = 0; nt < 4; ++nt)
                acc[mt][nt] = __builtin_amdgcn_mfma_f32_16x16x32_bf16(afr[mt], bfr[nt], acc[mt][nt], 0, 0, 0);
    }

    // ---- epilogue: h2 = mish(acc + b2), layer3 partial dot with W3 ----
    float b2c[4], w3c[4];
#pragma unroll
    for (int nt = 0; nt < 4; ++nt) {
        int col = w * 64 + nt * 16 + lo;
        b2c[nt] = b2[col];
        w3c[nt] = W3[col];
    }
#pragma unroll
    for (int mt = 0; mt < 4; ++mt) {
        float part[4] = {0.f, 0.f, 0.f, 0.f};
#pragma unroll
        for (int nt = 0; nt < 4; ++nt) {
#pragma unroll
            for (int r = 0; r < 4; ++r) {
                float h2 = mish_f(acc[mt][nt][r] + b2c[nt]);
                part[r] = fmaf(h2, w3c[nt], part[r]);
            }
        }
#pragma unroll
        for (int r = 0; r < 4; ++r) {
            float v = part[r];
            v += __shfl_xor(v, 1);
            v += __shfl_xor(v, 2);
            v += __shfl_xor(v, 4);
            v += __shfl_xor(v, 8);
            if (lo == 0) qpart[w][mt * 16 + q * 4 + r] = v;
        }
    }
    __syncthreads();
    if (t < 64) {
        float qv = qpart[0][t] + qpart[1][t] + qpart[2][t] + qpart[3][t] + b3[0];
        qk[((size_t)b * 64 + s0) * 8 + t] = qv;   // row t = sl*8 + k
    }
}

// ---------------- final: q1[b,i] = mean_s qk[b,s,perm[b,s,i]] ----------------
__global__ __launch_bounds__(256) void final_kernel(
        const float* __restrict__ qk,
        const int* __restrict__ perm,
        float* __restrict__ out) {
    __shared__ float qs[4][512];
    __shared__ int ps[4][512];
    int t = threadIdx.x;
    int w = t >> 6;
    int lane = t & 63;
    int b = blockIdx.x * 4 + w;
    for (int r = 0; r < 8; ++r) {
        qs[w][r * 64 + lane] = qk[(size_t)b * 512 + r * 64 + lane];
        ps[w][r * 64 + lane] = perm[(size_t)b * 512 + r * 64 + lane];
    }
    __syncthreads();
    int i = lane & 7;
    int s0 = lane >> 3;
    float v = 0.0f;
    for (int s = s0; s < 64; s += 8) v += qs[w][s * 8 + ps[w][s * 8 + i]];
    v += __shfl_xor(v, 8);
    v += __shfl_xor(v, 16);
    v += __shfl_xor(v, 32);
    if (lane < 8) {
        float r = v * (1.0f / 64.0f);
        out[b * 8 + i] = r;
        out[4096 + b * 8 + i] = r;
    }
}

extern "C" void kernel_launch(void* const* d_in, const int* in_sizes, int n_in,
                              void* d_out, int out_size, void* d_ws, size_t ws_size,
                              hipStream_t stream) {
    const float* state  = (const float*)d_in[0];
    const float* action = (const float*)d_in[1];
    const float* W1     = (const float*)d_in[2];
    const float* b1     = (const float*)d_in[3];
    const float* W2     = (const float*)d_in[4];
    const float* b2     = (const float*)d_in[5];
    const float* W3     = (const float*)d_in[6];
    const float* b3     = (const float*)d_in[7];
    const int*   perm   = (const int*)d_in[8];
    float* out = (float*)d_out;

    char* ws = (char*)d_ws;
    float*    obsW = (float*)ws;                                   // 0.5 MB
    float*    actW = (float*)(ws + 524288);                        // 32 MB
    ushort_t* W2T  = (ushort_t*)(ws + 524288 + 33554432);          // 128 KB
    float*    qk   = (float*)(ws + 524288 + 33554432 + 131072);    // 1 MB

    prep_kernel<<<576, 256, 0, stream>>>(state, action, W1, b1, W2, obsW, actW, W2T);
    main_kernel<<<4096, 256, 0, stream>>>(obsW, actW, W2T, perm, b2, W3, b3, qk);
    final_kernel<<<128, 256, 0, stream>>>(qk, perm, out);
}

// Round 3
// 184.829 us; speedup vs baseline: 1.1357x; 1.0758x over previous
//
#include <hip/hip_runtime.h>
#include <hip/hip_bf16.h>

typedef unsigned short ushort_t;
typedef __attribute__((ext_vector_type(8))) short short8;
typedef __attribute__((ext_vector_type(4))) float floatx4;

// B=512, S=64, N=8, D=64, A=16, H=256, IN_DIM=640

__device__ __forceinline__ float mish_f(float x) {
    float e = __expf(x);
    float w = fmaf(e, e + 2.0f, 2.0f);   // e^2x + 2e^x + 2, >= 2
    return x - 2.0f * x * __builtin_amdgcn_rcpf(w);
}

__device__ __forceinline__ unsigned f2bf_u(float f) {
    unsigned int u = __float_as_uint(f);
    return (u + 0x7fffu + ((u >> 16) & 1u)) >> 16;  // RNE
}

// ---------------- prep (fused, highly parallel) ----------------
// blocks [0,2048):    obsW partials, (b = bid>>2, kc = bid&3), atomicAdd into obsW
// blocks [2048,6144): actW bf16,     (idx = bid-2048, b = idx>>3, j = idx&7)
// blocks [6144,6208): W2T bf16 transpose
__global__ __launch_bounds__(256) void prep_kernel(
        const float* __restrict__ state,
        const float* __restrict__ action,
        const float* __restrict__ W1,
        const float* __restrict__ W2,
        float* __restrict__ obsW,
        ushort_t* __restrict__ actW,
        ushort_t* __restrict__ W2T) {
    int bid = blockIdx.x;
    int t = threadIdx.x;
    if (bid < 2048) {
        int b = bid >> 2;
        int kc = bid & 3;
        const float* stp = state + (size_t)b * 512 + kc * 128;  // wave-uniform -> s_load
        const float* w1p = W1 + (size_t)(kc * 128) * 256 + t;
        float a0 = 0.f, a1 = 0.f, a2 = 0.f, a3 = 0.f;
#pragma unroll 8
        for (int f = 0; f < 128; f += 4) {
            a0 = fmaf(stp[f + 0], w1p[(f + 0) * 256], a0);
            a1 = fmaf(stp[f + 1], w1p[(f + 1) * 256], a1);
            a2 = fmaf(stp[f + 2], w1p[(f + 2) * 256], a2);
            a3 = fmaf(stp[f + 3], w1p[(f + 3) * 256], a3);
        }
        atomicAdd(&obsW[b * 256 + t], (a0 + a1) + (a2 + a3));
    } else if (bid < 6144) {
        int idx = bid - 2048;
        int b = idx >> 3;
        int j = idx & 7;
        const float* acp = action + (size_t)b * 128;            // wave-uniform -> s_load
        const float* W1a = W1 + (size_t)(512 + j * 16) * 256;
        float acc[8];
#pragma unroll
        for (int n = 0; n < 8; ++n) acc[n] = 0.f;
#pragma unroll
        for (int a = 0; a < 16; ++a) {
            float w = W1a[a * 256 + t];
#pragma unroll
            for (int n = 0; n < 8; ++n)
                acc[n] = fmaf(acp[n * 16 + a], w, acc[n]);
        }
#pragma unroll
        for (int n = 0; n < 8; ++n)
            actW[(((size_t)b * 8 + n) * 8 + j) * 256 + t] = (ushort_t)f2bf_u(acc[n]);
    } else {
        int n = (bid - 6144) * 4 + (t >> 6);
        int klo = (t & 63);
        for (int kk = 0; kk < 4; ++kk) {
            int k = kk * 64 + klo;
            W2T[n * 256 + k] = (ushort_t)f2bf_u(W2[k * 256 + n]);
        }
    }
}

// ---------------- main: build h1 (prefix+mish), layer2 MFMA, layer3 dot ----------------
#define LDK 264  // padded LDS row stride in bf16 elems (16B-aligned rows)

__global__ __launch_bounds__(256, 4) void main_kernel(
        const float* __restrict__ obsW, const ushort_t* __restrict__ actW,
        const ushort_t* __restrict__ W2T, const int* __restrict__ perm,
        const float* __restrict__ b1, const float* __restrict__ b2,
        const float* __restrict__ W3, const float* __restrict__ b3,
        float* __restrict__ qk) {
    __shared__ ushort_t h1[64 * LDK];   // 33.8 KB
    __shared__ float obsb[256];
    __shared__ int perm_s[64];
    __shared__ float qpart[4][64];

    int t = threadIdx.x;
    int bid = blockIdx.x;
    // XCD swizzle: all 8 s-group blocks of one b share blockIdx%8 -> same XCD L2
    int b = (bid & 7) * 64 + ((bid >> 3) & 63);
    int sg = bid >> 9;
    int s0 = sg * 8;

    obsb[t] = obsW[b * 256 + t] + b1[t];
    if (t < 64) perm_s[t] = perm[((size_t)b * 64 + s0) * 8 + t];
    __syncthreads();

    // ---- build h1 rows (row = sl*8 + j): 2 cols per thread, 4 sl per thread ----
    const ushort_t* actb = actW + (size_t)b * 64 * 256;
    {
        int half = t >> 7;
        int c = (t & 127) * 2;
        float ob0 = obsb[c], ob1 = obsb[c + 1];
#pragma unroll
        for (int sl2 = 0; sl2 < 4; ++sl2) {
            int sl = half * 4 + sl2;
            // prefetch the 8 gathered bf16x2 values before the dependent chain
            unsigned av[8];
#pragma unroll
            for (int j = 0; j < 8; ++j) {
                int p = perm_s[sl * 8 + j];
                av[j] = *reinterpret_cast<const unsigned*>(actb + (p * 8 + j) * 256 + c);
            }
            float r0 = ob0, r1 = ob1;
#pragma unroll
            for (int j = 0; j < 8; ++j) {
                r0 += __uint_as_float(av[j] << 16);
                r1 += __uint_as_float(av[j] & 0xffff0000u);
                __hip_bfloat162 pk = __float22bfloat162_rn(make_float2(mish_f(r0), mish_f(r1)));
                *reinterpret_cast<__hip_bfloat162*>(&h1[(sl * 8 + j) * LDK + c]) = pk;
            }
        }
    }
    __syncthreads();

    // ---- layer2: M=64, N=256, K=256; wave w owns 64-col N-strip ----
    int w = t >> 6;
    int lo = t & 15;
    int q = (t >> 4) & 3;

    floatx4 acc[4][4];
#pragma unroll
    for (int mt = 0; mt < 4; ++mt)
#pragma unroll
        for (int nt = 0; nt < 4; ++nt)
            acc[mt][nt] = (floatx4){0.f, 0.f, 0.f, 0.f};

    const ushort_t* w2base = W2T + ((size_t)(w * 64 + lo)) * 256 + q * 8;

#pragma unroll
    for (int ks = 0; ks < 8; ++ks) {
        short8 afr[4];
#pragma unroll
        for (int mt = 0; mt < 4; ++mt)
            afr[mt] = *reinterpret_cast<const short8*>(&h1[(mt * 16 + lo) * LDK + ks * 32 + q * 8]);
        short8 bfr[4];
#pragma unroll
        for (int nt = 0; nt < 4; ++nt)
            bfr[nt] = *reinterpret_cast<const short8*>(w2base + nt * 16 * 256 + ks * 32);
#pragma unroll
        for (int mt = 0; mt < 4; ++mt)
#pragma unroll
            for (int nt = 0; nt < 4; ++nt)
                acc[mt][nt] = __builtin_amdgcn_mfma_f32_16x16x32_bf16(afr[mt], bfr[nt], acc[mt][nt], 0, 0, 0);
    }

    // ---- epilogue: h2 = mish(acc + b2), layer3 partial dot with W3 ----
    float b2c[4], w3c[4];
#pragma unroll
    for (int nt = 0; nt < 4; ++nt) {
        int col = w * 64 + nt * 16 + lo;
        b2c[nt] = b2[col];
        w3c[nt] = W3[col];
    }
#pragma unroll
    for (int mt = 0; mt < 4; ++mt) {
        float part[4] = {0.f, 0.f, 0.f, 0.f};
#pragma unroll
        for (int nt = 0; nt < 4; ++nt) {
#pragma unroll
            for (int r = 0; r < 4; ++r) {
                float h2 = mish_f(acc[mt][nt][r] + b2c[nt]);
                part[r] = fmaf(h2, w3c[nt], part[r]);
            }
        }
#pragma unroll
        for (int r = 0; r < 4; ++r) {
            float v = part[r];
            v += __shfl_xor(v, 1);
            v += __shfl_xor(v, 2);
            v += __shfl_xor(v, 4);
            v += __shfl_xor(v, 8);
            if (lo == 0) qpart[w][mt * 16 + q * 4 + r] = v;
        }
    }
    __syncthreads();
    if (t < 64) {
        float qv = qpart[0][t] + qpart[1][t] + qpart[2][t] + qpart[3][t] + b3[0];
        qk[((size_t)b * 64 + s0) * 8 + t] = qv;   // row t = sl*8 + k
    }
}

// ---------------- final: q1[b,i] = mean_s qk[b,s,perm[b,s,i]] ----------------
__global__ __launch_bounds__(256) void final_kernel(
        const float* __restrict__ qk,
        const int* __restrict__ perm,
        float* __restrict__ out) {
    __shared__ float qs[4][512];
    __shared__ int ps[4][512];
    int t = threadIdx.x;
    int w = t >> 6;
    int lane = t & 63;
    int b = blockIdx.x * 4 + w;
    for (int r = 0; r < 8; ++r) {
        qs[w][r * 64 + lane] = qk[(size_t)b * 512 + r * 64 + lane];
        ps[w][r * 64 + lane] = perm[(size_t)b * 512 + r * 64 + lane];
    }
    __syncthreads();
    int i = lane & 7;
    int s0 = lane >> 3;
    float v = 0.0f;
    for (int s = s0; s < 64; s += 8) v += qs[w][s * 8 + ps[w][s * 8 + i]];
    v += __shfl_xor(v, 8);
    v += __shfl_xor(v, 16);
    v += __shfl_xor(v, 32);
    if (lane < 8) {
        float r = v * (1.0f / 64.0f);
        out[b * 8 + i] = r;
        out[4096 + b * 8 + i] = r;
    }
}

extern "C" void kernel_launch(void* const* d_in, const int* in_sizes, int n_in,
                              void* d_out, int out_size, void* d_ws, size_t ws_size,
                              hipStream_t stream) {
    const float* state  = (const float*)d_in[0];
    const float* action = (const float*)d_in[1];
    const float* W1     = (const float*)d_in[2];
    const float* b1     = (const float*)d_in[3];
    const float* W2     = (const float*)d_in[4];
    const float* b2     = (const float*)d_in[5];
    const float* W3     = (const float*)d_in[6];
    const float* b3     = (const float*)d_in[7];
    const int*   perm   = (const int*)d_in[8];
    float* out = (float*)d_out;

    char* ws = (char*)d_ws;
    float*    obsW = (float*)ws;                                  // 512*256*4   = 0.5 MB
    ushort_t* actW = (ushort_t*)(ws + 524288);                    // 512*64*256*2 = 16 MB
    ushort_t* W2T  = (ushort_t*)(ws + 524288 + 16777216);         // 128 KB
    float*    qk   = (float*)(ws + 524288 + 16777216 + 131072);   // 1 MB

    hipMemsetAsync(obsW, 0, 512 * 256 * sizeof(float), stream);
    prep_kernel<<<6208, 256, 0, stream>>>(state, action, W1, W2, obsW, actW, W2T);
    main_kernel<<<4096, 256, 0, stream>>>(obsW, actW, W2T, perm, b1, b2, W3, b3, qk);
    final_kernel<<<128, 256, 0, stream>>>(qk, perm, out);
}

// Round 4
// 181.842 us; speedup vs baseline: 1.1544x; 1.0164x over previous
//
#include <hip/hip_runtime.h>
#include <hip/hip_bf16.h>

typedef unsigned short ushort_t;
typedef __attribute__((ext_vector_type(8))) short short8;
typedef __attribute__((ext_vector_type(4))) float floatx4;

// B=512, S=64, N=8, D=64, A=16, H=256, IN_DIM=640

__device__ __forceinline__ float mish_f(float x) {
    float e = __expf(x);
    float w = fmaf(e, e + 2.0f, 2.0f);   // e^2x + 2e^x + 2, >= 2
    return x - 2.0f * x * __builtin_amdgcn_rcpf(w);
}

__device__ __forceinline__ unsigned f2bf_u(float f) {
    unsigned int u = __float_as_uint(f);
    return (u + 0x7fffu + ((u >> 16) & 1u)) >> 16;  // RNE
}

// ---------------- prep ----------------
// blocks [0,512):     obsW[b][t] = state[b]@W1obs + b1  (fp32, plain store)
// blocks [512,4608):  actW bf16, one block per (b = idx>>3, j = idx&7)
// blocks [4608,4672): W2T bf16 transpose
__global__ __launch_bounds__(256) void prep_kernel(
        const float* __restrict__ state,
        const float* __restrict__ action,
        const float* __restrict__ W1,
        const float* __restrict__ b1,
        const float* __restrict__ W2,
        float* __restrict__ obsW,
        ushort_t* __restrict__ actW,
        ushort_t* __restrict__ W2T) {
    int bid = blockIdx.x;
    int t = threadIdx.x;
    if (bid < 512) {
        int b = bid;
        const float* stp = state + (size_t)b * 512;   // wave-uniform -> s_load
        const float* w1p = W1 + t;
        float a0 = 0.f, a1 = 0.f, a2 = 0.f, a3 = 0.f;
#pragma unroll 8
        for (int f = 0; f < 512; f += 4) {
            a0 = fmaf(stp[f + 0], w1p[(f + 0) * 256], a0);
            a1 = fmaf(stp[f + 1], w1p[(f + 1) * 256], a1);
            a2 = fmaf(stp[f + 2], w1p[(f + 2) * 256], a2);
            a3 = fmaf(stp[f + 3], w1p[(f + 3) * 256], a3);
        }
        obsW[b * 256 + t] = (a0 + a1) + (a2 + a3) + b1[t];
    } else if (bid < 4608) {
        int idx = bid - 512;
        int b = idx >> 3;
        int j = idx & 7;
        const float* acp = action + (size_t)b * 128;  // wave-uniform -> s_load
        const float* W1a = W1 + (size_t)(512 + j * 16) * 256;
        float acc[8];
#pragma unroll
        for (int n = 0; n < 8; ++n) acc[n] = 0.f;
#pragma unroll
        for (int a = 0; a < 16; ++a) {
            float w = W1a[a * 256 + t];
#pragma unroll
            for (int n = 0; n < 8; ++n)
                acc[n] = fmaf(acp[n * 16 + a], w, acc[n]);
        }
#pragma unroll
        for (int n = 0; n < 8; ++n)
            actW[(((size_t)b * 8 + n) * 8 + j) * 256 + t] = (ushort_t)f2bf_u(acc[n]);
    } else {
        int n = (bid - 4608) * 4 + (t >> 6);
        int klo = (t & 63);
        for (int kk = 0; kk < 4; ++kk) {
            int k = kk * 64 + klo;
            W2T[n * 256 + k] = (ushort_t)f2bf_u(W2[k * 256 + n]);
        }
    }
}

// ---------------- main: h1 build + layer2 MFMA + layer3 + perm-gather reduce ----------------
#define LDK 264  // padded LDS row stride in bf16 elems (16B-aligned rows)

__global__ __launch_bounds__(512, 8) void main_kernel(
        const float* __restrict__ obsW, const ushort_t* __restrict__ actW,
        const ushort_t* __restrict__ W2T, const int* __restrict__ perm,
        const float* __restrict__ b2,
        const float* __restrict__ W3, const float* __restrict__ b3,
        float* __restrict__ out) {
    __shared__ ushort_t h1[64 * LDK];   // 33.8 KB
    __shared__ float obsb[256];
    __shared__ int perm_s[64];
    __shared__ float qpart[8][64];
    __shared__ float qv_s[64];

    int t = threadIdx.x;
    int bid = blockIdx.x;
    // XCD swizzle: all 8 s-group blocks of one b share blockIdx%8 -> same XCD L2
    int b = (bid & 7) * 64 + ((bid >> 3) & 63);
    int sg = bid >> 9;
    int s0 = sg * 8;

    if (t < 256) obsb[t] = obsW[b * 256 + t];            // includes b1
    else if (t < 320) perm_s[t - 256] = perm[((size_t)b * 64 + s0) * 8 + (t - 256)];
    __syncthreads();

    // ---- build h1 rows (row = sl*8 + j): 2 cols x 2 sl-chains per thread ----
    const ushort_t* actb = actW + (size_t)b * 64 * 256;
    {
        int slg = t >> 7;            // 0..3
        int c = (t & 127) * 2;
        float ob0 = obsb[c], ob1 = obsb[c + 1];
#pragma unroll
        for (int sl2 = 0; sl2 < 2; ++sl2) {
            int sl = slg * 2 + sl2;
            unsigned av[8];
#pragma unroll
            for (int j = 0; j < 8; ++j) {
                int p = perm_s[sl * 8 + j];
                av[j] = *reinterpret_cast<const unsigned*>(actb + (p * 8 + j) * 256 + c);
            }
            float r0 = ob0, r1 = ob1;
#pragma unroll
            for (int j = 0; j < 8; ++j) {
                r0 += __uint_as_float(av[j] << 16);
                r1 += __uint_as_float(av[j] & 0xffff0000u);
                __hip_bfloat162 pk = __float22bfloat162_rn(make_float2(mish_f(r0), mish_f(r1)));
                *reinterpret_cast<__hip_bfloat162*>(&h1[(sl * 8 + j) * LDK + c]) = pk;
            }
        }
    }
    __syncthreads();

    // ---- layer2: M=64, N=256, K=256; wave w (0..7) owns 32-col N-strip ----
    int w = t >> 6;
    int L = t & 63;
    int lo = L & 15;
    int q = L >> 4;

    floatx4 acc[4][2];
#pragma unroll
    for (int mt = 0; mt < 4; ++mt)
#pragma unroll
        for (int nt = 0; nt < 2; ++nt)
            acc[mt][nt] = (floatx4){0.f, 0.f, 0.f, 0.f};

    const ushort_t* w2base = W2T + ((size_t)(w * 32 + lo)) * 256 + q * 8;

#pragma unroll
    for (int ks = 0; ks < 8; ++ks) {
        short8 afr[4];
#pragma unroll
        for (int mt = 0; mt < 4; ++mt)
            afr[mt] = *reinterpret_cast<const short8*>(&h1[(mt * 16 + lo) * LDK + ks * 32 + q * 8]);
#pragma unroll
        for (int nt = 0; nt < 2; ++nt) {
            short8 bfr = *reinterpret_cast<const short8*>(w2base + nt * 16 * 256 + ks * 32);
#pragma unroll
            for (int mt = 0; mt < 4; ++mt)
                acc[mt][nt] = __builtin_amdgcn_mfma_f32_16x16x32_bf16(afr[mt], bfr, acc[mt][nt], 0, 0, 0);
        }
    }

    // ---- epilogue: h2 = mish(acc + b2), layer3 partial dot with W3 ----
    float b2c[2], w3c[2];
#pragma unroll
    for (int nt = 0; nt < 2; ++nt) {
        int col = w * 32 + nt * 16 + lo;
        b2c[nt] = b2[col];
        w3c[nt] = W3[col];
    }
#pragma unroll
    for (int mt = 0; mt < 4; ++mt) {
        float part[4] = {0.f, 0.f, 0.f, 0.f};
#pragma unroll
        for (int nt = 0; nt < 2; ++nt) {
#pragma unroll
            for (int r = 0; r < 4; ++r) {
                float h2 = mish_f(acc[mt][nt][r] + b2c[nt]);
                part[r] = fmaf(h2, w3c[nt], part[r]);
            }
        }
#pragma unroll
        for (int r = 0; r < 4; ++r) {
            float v = part[r];
            v += __shfl_xor(v, 1);
            v += __shfl_xor(v, 2);
            v += __shfl_xor(v, 4);
            v += __shfl_xor(v, 8);
            if (lo == 0) qpart[w][mt * 16 + q * 4 + r] = v;
        }
    }
    __syncthreads();
    if (t < 64) {
        float qv = b3[0];
#pragma unroll
        for (int ww = 0; ww < 8; ++ww) qv += qpart[ww][t];
        qv_s[t] = qv;    // row t = sl*8 + k
    }
    __syncthreads();
    // fused final: partial over this block's 8 s-values, atomic into out
    if (t < 8) {
        float p = 0.f;
#pragma unroll
        for (int sl = 0; sl < 8; ++sl)
            p += qv_s[sl * 8 + perm_s[sl * 8 + t]];
        p *= (1.0f / 64.0f);
        atomicAdd(&out[b * 8 + t], p);
        atomicAdd(&out[4096 + b * 8 + t], p);
    }
}

extern "C" void kernel_launch(void* const* d_in, const int* in_sizes, int n_in,
                              void* d_out, int out_size, void* d_ws, size_t ws_size,
                              hipStream_t stream) {
    const float* state  = (const float*)d_in[0];
    const float* action = (const float*)d_in[1];
    const float* W1     = (const float*)d_in[2];
    const float* b1     = (const float*)d_in[3];
    const float* W2     = (const float*)d_in[4];
    const float* b2     = (const float*)d_in[5];
    const float* W3     = (const float*)d_in[6];
    const float* b3     = (const float*)d_in[7];
    const int*   perm   = (const int*)d_in[8];
    float* out = (float*)d_out;

    char* ws = (char*)d_ws;
    float*    obsW = (float*)ws;                          // 512*256*4    = 0.5 MB
    ushort_t* actW = (ushort_t*)(ws + 524288);            // 512*64*256*2 = 16 MB
    ushort_t* W2T  = (ushort_t*)(ws + 524288 + 16777216); // 128 KB

    hipMemsetAsync(out, 0, (size_t)out_size * sizeof(float), stream);
    prep_kernel<<<4672, 256, 0, stream>>>(state, action, W1, b1, W2, obsW, actW, W2T);
    main_kernel<<<4096, 512, 0, stream>>>(obsW, actW, W2T, perm, b2, W3, b3, out);
}